// Round 1
// baseline (4795.860 us; speedup 1.0000x reference)
//
#include <hip/hip_runtime.h>
#include <math.h>

#define BB 8
#define VV 2048
#define CC 32
#define TT 32
#define JJ 8192   // 4*V

typedef unsigned short u16;
typedef unsigned int u32;

struct P {
  // inputs
  const float* Mvv; const int* ncol; const float* vh0; const float* ch0;
  const float* v0_wih; const float* v0_whh; const float* v0_bih; const float* v0_bhh;
  const float* v1_wih; const float* v1_whh; const float* v1_bih; const float* v1_bhh;
  const float* c_wih; const float* c_whh; const float* c_bih; const float* c_bhh;
  const float* cmsg_w; const float* cmsg_b; const float* vmsg_w; const float* vmsg_b;
  const float* vote_w; const float* vote_b;
  // workspace
  u16* w0x; u16* w0h; u16* w1x; u16* w1h; u16* wv;
  float* rs0; int* adj_cnt; int* adj_cols;
  float* h0; float* m0; float* h1; float* m1; float* chb; float* cm;
  float* g0p; float* g1p; float* p1p; float* vmp; float* pacc;
  float* out;
};

__device__ __forceinline__ u16 f2bf(float f) {
  u32 x = __float_as_uint(f);
  u32 r = (x + 0x7fffu + ((x >> 16) & 1u)) >> 16;
  return (u16)r;
}

__device__ __forceinline__ float4 bf4(uint2 u) {
  float4 f;
  f.x = __uint_as_float(u.x << 16);
  f.y = __uint_as_float(u.x & 0xffff0000u);
  f.z = __uint_as_float(u.y << 16);
  f.w = __uint_as_float(u.y & 0xffff0000u);
  return f;
}

__device__ __forceinline__ float sigm(float x) { return 1.f / (1.f + expf(-x)); }

// ---- weight transpose+convert: dst[k][j] = bf16(src[j][colOff+k]) ----
__global__ __launch_bounds__(256) void kTrans(const float* __restrict__ src, int srcStride,
                                              int colOff, int nJt,
                                              u16* __restrict__ dst, int dstStride) {
  int bx = blockIdx.x, tid = threadIdx.x;
  int jt = bx % nJt, kt = bx / nJt;
  __shared__ float tile[64][65];
  int r = tid >> 4, cg = (tid & 15) * 4;
#pragma unroll
  for (int rr = 0; rr < 4; ++rr) {
    int jl = r + rr * 16;
    const float* sp = src + (size_t)(jt * 64 + jl) * srcStride + colOff + kt * 64 + cg;
    float4 v = *(const float4*)sp;
    tile[jl][cg] = v.x; tile[jl][cg + 1] = v.y; tile[jl][cg + 2] = v.z; tile[jl][cg + 3] = v.w;
  }
  __syncthreads();
#pragma unroll
  for (int rr = 0; rr < 4; ++rr) {
    int kl = r + rr * 16;
    u16 o0 = f2bf(tile[cg + 0][kl]);
    u16 o1 = f2bf(tile[cg + 1][kl]);
    u16 o2 = f2bf(tile[cg + 2][kl]);
    u16 o3 = f2bf(tile[cg + 3][kl]);
    uint2 pk = make_uint2((u32)o0 | ((u32)o1 << 16), (u32)o2 | ((u32)o3 << 16));
    *(uint2*)(dst + (size_t)(kt * 64 + kl) * dstStride + jt * 64 + cg) = pk;
  }
}

// ---- rs0[j] = sum_{k<2048} v0_wih[j][k] ----
__global__ __launch_bounds__(256) void kRs0(P p) {
  int wid = threadIdx.x >> 6, lane = threadIdx.x & 63;
  int row = blockIdx.x * 4 + wid;
  const float* sp = p.v0_wih + (size_t)row * (2 * VV);
  float s = 0.f;
  for (int i = lane; i < VV; i += 64) s += sp[i];
#pragma unroll
  for (int d = 32; d > 0; d >>= 1) s += __shfl_down(s, d, 64);
  if (lane == 0) p.rs0[row] = s;
}

// ---- adjacency list: one wave per (b,u) row of Mvv ----
__global__ __launch_bounds__(256) void kAdj(P p) {
  int wid = threadIdx.x >> 6, lane = threadIdx.x & 63;
  int row = blockIdx.x * 4 + wid;   // b*2048+u
  const float* mp = p.Mvv + (size_t)row * VV;
  int* cols = p.adj_cols + (size_t)row * 64;
  int cnt = 0;
  for (int it = 0; it < 32; ++it) {
    float v = mp[it * 64 + lane];
    bool nz = v > 0.5f;
    unsigned long long mk = __ballot(nz);
    if (nz) {
      int pos = cnt + (int)__popcll(mk & ((1ull << lane) - 1ull));
      if (pos < 64) cols[pos] = it * 64 + lane;
    }
    cnt += (int)__popcll(mk);
  }
  if (lane == 0) p.adj_cnt[row] = cnt > 64 ? 64 : cnt;
}

// ---- state init ----
__global__ __launch_bounds__(256) void kInit(P p) {
  int i = blockIdx.x * 256 + threadIdx.x;  // 16384
  p.h0[i] = p.vh0[i];
  p.h1[i] = p.vh0[BB * VV + i];
  p.m0[i] = 0.f; p.m1[i] = 0.f;
  if (i < BB * CC) { p.chb[i] = p.ch0[i]; p.cm[i] = 0.f; }
  if (i < 8) p.pacc[i] = 0.f;
}

// ---- shared GEMV-partial body: out[b][j..j+3] = sum over 128-k chunk ----
__device__ __forceinline__ void gemv_body(const u16* __restrict__ Wt, int wstride,
                                          const float* Xs, int j, int k0,
                                          float* __restrict__ outp) {
  float4 acc[8];
#pragma unroll
  for (int b = 0; b < 8; ++b) acc[b] = make_float4(0.f, 0.f, 0.f, 0.f);
  const u16* wp = Wt + (size_t)k0 * wstride + j;
  for (int k = 0; k < 128; k += 4) {
    uint2 w0 = *(const uint2*)(wp);
    uint2 w1 = *(const uint2*)(wp + (size_t)wstride);
    uint2 w2 = *(const uint2*)(wp + 2 * (size_t)wstride);
    uint2 w3 = *(const uint2*)(wp + 3 * (size_t)wstride);
    wp += 4 * (size_t)wstride;
    float4 f0 = bf4(w0), f1 = bf4(w1), f2 = bf4(w2), f3 = bf4(w3);
#pragma unroll
    for (int b = 0; b < 8; ++b) {
      float4 xv = *(const float4*)(Xs + (b << 7) + k);
      acc[b].x = fmaf(f0.x, xv.x, acc[b].x);
      acc[b].y = fmaf(f0.y, xv.x, acc[b].y);
      acc[b].z = fmaf(f0.z, xv.x, acc[b].z);
      acc[b].w = fmaf(f0.w, xv.x, acc[b].w);
      acc[b].x = fmaf(f1.x, xv.y, acc[b].x);
      acc[b].y = fmaf(f1.y, xv.y, acc[b].y);
      acc[b].z = fmaf(f1.z, xv.y, acc[b].z);
      acc[b].w = fmaf(f1.w, xv.y, acc[b].w);
      acc[b].x = fmaf(f2.x, xv.z, acc[b].x);
      acc[b].y = fmaf(f2.y, xv.z, acc[b].y);
      acc[b].z = fmaf(f2.z, xv.z, acc[b].z);
      acc[b].w = fmaf(f2.w, xv.z, acc[b].w);
      acc[b].x = fmaf(f3.x, xv.w, acc[b].x);
      acc[b].y = fmaf(f3.y, xv.w, acc[b].y);
      acc[b].z = fmaf(f3.z, xv.w, acc[b].z);
      acc[b].w = fmaf(f3.w, xv.w, acc[b].w);
    }
  }
#pragma unroll
  for (int b = 0; b < 8; ++b) *(float4*)(outp + (size_t)b * wstride + j) = acc[b];
}

// ---- kA: gates0 partials (incl. inline SpMV of muled_v), part1 partials, vmsg partials ----
__global__ __launch_bounds__(256) void kA(P p) {
  int bx = blockIdx.x, tid = threadIdx.x;
  __shared__ __align__(16) float Xs[BB * 128];
  const u16* Wt; int wstride, j0, k0; float* outp;
  int mode; const float* Xsrc = nullptr;
  if (bx < 256) {                       // gates0: 8 jt x 32 kc
    int jt = bx & 7, kc = bx >> 3;
    j0 = jt * 1024;
    if (kc < 16) { Wt = p.w0x; k0 = kc * 128; mode = 0; }
    else         { Wt = p.w0h; k0 = (kc - 16) * 128; mode = 1; Xsrc = p.h0; }
    wstride = JJ;
    outp = p.g0p + (size_t)kc * BB * JJ;
  } else if (bx < 384) {                // part1 = h1 @ v1_whh.T : 8 jt x 16 kc
    int i = bx - 256; int jt = i & 7, kc = i >> 3;
    j0 = jt * 1024; Wt = p.w1h; k0 = kc * 128; mode = 1; Xsrc = p.h1;
    wstride = JJ; outp = p.p1p + (size_t)kc * BB * JJ;
  } else {                              // vmsg partials: 2 jt x 16 kc
    int i = bx - 384; int jt = i & 1, kc = i >> 1;
    j0 = jt * 1024; Wt = p.wv; k0 = kc * 128; mode = 1; Xsrc = p.h1;
    wstride = VV; outp = p.vmp + (size_t)kc * BB * VV;
  }
  if (mode == 0) {   // muled_v chunk via adjacency gather from h1
#pragma unroll
    for (int e = 0; e < 4; ++e) {
      int idx = tid + e * 256; int b = idx >> 7, uu = idx & 127;
      int row = b * VV + k0 + uu;
      int cnt = p.adj_cnt[row];
      const int* cp = p.adj_cols + (size_t)row * 64;
      const float* hb = p.h1 + b * VV;
      float s = 0.f;
      for (int q = 0; q < cnt; ++q) s += hb[cp[q]];
      Xs[b * 128 + uu] = s;
    }
  } else {
#pragma unroll
    for (int e = 0; e < 4; ++e) {
      int idx = tid + e * 256; int b = idx >> 7, kk = idx & 127;
      Xs[b * 128 + kk] = Xsrc[b * VV + k0 + kk];
    }
  }
  __syncthreads();
  gemv_body(Wt, wstride, Xs, j0 + tid * 4, k0, outp);
}

// ---- kB: reduce gates0 -> h0',m0'; color LSTM update (block 64) ----
__global__ __launch_bounds__(256) void kB(P p, int t) {
  int bx = blockIdx.x, tid = threadIdx.x;
  const float* chp = p.chb + (t & 1) * BB * CC;
  float* chq = p.chb + ((t + 1) & 1) * BB * CC;
  if (bx < 64) {
    __shared__ float scs[BB * CC];
    __shared__ float scv[BB];
    {
      int b = tid >> 5, jc = tid & 31;
      float a = p.cmsg_b[jc];
#pragma unroll
      for (int k = 0; k < 32; ++k) a += chp[b * CC + k] * p.cmsg_w[jc * CC + k];
      a = fmaxf(a, 0.f);
      scs[tid] = (jc < p.ncol[b]) ? a : 0.f;
    }
    __syncthreads();
    if (tid < 8) {
      float s = 0.f;
      for (int jc = 0; jc < 32; ++jc) s += scs[tid * 32 + jc];
      scv[tid] = s;
    }
    __syncthreads();
    int flat = bx * 256 + tid;            // = b*2048 + tt
    int b = flat >> 11, tt2 = flat & 2047;
    float g4[4];
#pragma unroll
    for (int g = 0; g < 4; ++g) {
      int jj = g * 2048 + tt2;
      float s = p.v0_bih[jj] + p.v0_bhh[jj] + scv[b] * p.rs0[jj];
      const float* gp = p.g0p + (size_t)b * JJ + jj;
#pragma unroll 8
      for (int sl = 0; sl < 32; ++sl) s += gp[(size_t)sl * BB * JJ];
      g4[g] = s;
    }
    float ig = sigm(g4[0]), fg = sigm(g4[1]), gg = tanhf(g4[2]), og = sigm(g4[3]);
    float mn = fg * p.m0[flat] + ig * gg;
    float hn = og * tanhf(mn);
    p.m0[flat] = mn; p.h0[flat] = hn;
  } else {
    // color LSTM: vsum reduce then cell update
    __shared__ float red[256];
    __shared__ float vs[BB];
    for (int b = 0; b < 8; ++b) {
      float ps = 0.f;
      for (int uu = tid; uu < VV; uu += 256) {
        float s = p.vmsg_b[uu];
        const float* vp = p.vmp + (size_t)b * VV + uu;
#pragma unroll
        for (int sl = 0; sl < 16; ++sl) s += vp[(size_t)sl * BB * VV];
        ps += fmaxf(s, 0.f);
      }
      red[tid] = ps;
      __syncthreads();
      for (int d = 128; d > 0; d >>= 1) {
        if (tid < d) red[tid] += red[tid + d];
        __syncthreads();
      }
      if (tid == 0) vs[b] = red[0];
      __syncthreads();
    }
    int b = tid >> 5, tc = tid & 31;
    int nc = p.ncol[b];
    float g4[4];
#pragma unroll
    for (int g = 0; g < 4; ++g) {
      int jc = g * 32 + tc;
      float s = p.c_bih[jc] + p.c_bhh[jc];
      float wsum = 0.f;
      for (int k = 0; k < nc; ++k) wsum += p.c_wih[jc * CC + k];
      s += vs[b] * wsum;
#pragma unroll
      for (int k = 0; k < 32; ++k) s += chp[b * CC + k] * p.c_whh[jc * CC + k];
      g4[g] = s;
    }
    float ig = sigm(g4[0]), fg = sigm(g4[1]), gg = tanhf(g4[2]), og = sigm(g4[3]);
    float mn = fg * p.cm[tid] + ig * gg;
    float hn = og * tanhf(mn);
    p.cm[tid] = mn; chq[tid] = hn;
  }
}

// ---- kC: gates1 partials = h0'(new) @ v1_wih.T ----
__global__ __launch_bounds__(256) void kC(P p) {
  int bx = blockIdx.x, tid = threadIdx.x;
  int jt = bx & 7, kc = bx >> 3;   // 8 x 16
  int j0 = jt * 1024, k0 = kc * 128;
  __shared__ __align__(16) float Xs[BB * 128];
#pragma unroll
  for (int e = 0; e < 4; ++e) {
    int idx = tid + e * 256; int b = idx >> 7, kk = idx & 127;
    Xs[b * 128 + kk] = p.h0[b * VV + k0 + kk];
  }
  __syncthreads();
  gemv_body(p.w1x, JJ, Xs, j0 + tid * 4, k0, p.g1p + (size_t)kc * BB * JJ);
}

// ---- kD: reduce gates1 + part1 -> h1', m1' ----
__global__ __launch_bounds__(256) void kD(P p) {
  int bx = blockIdx.x, tid = threadIdx.x;
  int flat = bx * 256 + tid;
  int b = flat >> 11, tt2 = flat & 2047;
  float g4[4];
#pragma unroll
  for (int g = 0; g < 4; ++g) {
    int jj = g * 2048 + tt2;
    float s = p.v1_bih[jj] + p.v1_bhh[jj];
    const float* gp = p.g1p + (size_t)b * JJ + jj;
    const float* pp = p.p1p + (size_t)b * JJ + jj;
#pragma unroll 8
    for (int sl = 0; sl < 16; ++sl) s += gp[(size_t)sl * BB * JJ] + pp[(size_t)sl * BB * JJ];
    g4[g] = s;
  }
  float ig = sigm(g4[0]), fg = sigm(g4[1]), gg = tanhf(g4[2]), og = sigm(g4[3]);
  float mn = fg * p.m1[flat] + ig * gg;
  float hn = og * tanhf(mn);
  p.m1[flat] = mn; p.h1[flat] = hn;
}

// ---- vote: per-u sigmoid then atomic mean accumulate ----
__global__ __launch_bounds__(256) void kV1(P p) {
  int bx = blockIdx.x, tid = threadIdx.x;
  int b = bx >> 3, ut = bx & 7;
  int u = ut * 256 + tid;
  __shared__ float hs[VV];
  for (int i = tid; i < VV; i += 256) hs[i] = p.h1[b * VV + i];
  __syncthreads();
  const float* wr = p.vote_w + (size_t)u * VV;
  float s = p.vote_b[u];
  for (int k = 0; k < VV; k += 4) {
    float4 w = *(const float4*)(wr + k);
    s += w.x * hs[k] + w.y * hs[k + 1] + w.z * hs[k + 2] + w.w * hs[k + 3];
  }
  float sg = sigm(s);
  atomicAdd(&p.pacc[b], sg);
}

__global__ __launch_bounds__(64) void kV2(P p) {
  int tid = threadIdx.x;
  if (tid < 8) p.out[tid] = sigm(p.pacc[tid] * (1.f / (float)VV));
}

extern "C" void kernel_launch(void* const* d_in, const int* in_sizes, int n_in,
                              void* d_out, int out_size, void* d_ws, size_t ws_size,
                              hipStream_t stream) {
  P p;
  p.Mvv    = (const float*)d_in[0];
  p.ncol   = (const int*)d_in[1];
  p.vh0    = (const float*)d_in[2];
  p.ch0    = (const float*)d_in[3];
  p.v0_wih = (const float*)d_in[4];
  p.v0_whh = (const float*)d_in[5];
  p.v0_bih = (const float*)d_in[6];
  p.v0_bhh = (const float*)d_in[7];
  p.v1_wih = (const float*)d_in[8];
  p.v1_whh = (const float*)d_in[9];
  p.v1_bih = (const float*)d_in[10];
  p.v1_bhh = (const float*)d_in[11];
  p.c_wih  = (const float*)d_in[12];
  p.c_whh  = (const float*)d_in[13];
  p.c_bih  = (const float*)d_in[14];
  p.c_bhh  = (const float*)d_in[15];
  p.cmsg_w = (const float*)d_in[16];
  p.cmsg_b = (const float*)d_in[17];
  p.vmsg_w = (const float*)d_in[18];
  p.vmsg_b = (const float*)d_in[19];
  p.vote_w = (const float*)d_in[20];
  p.vote_b = (const float*)d_in[21];

  char* w = (char*)d_ws;
  size_t o = 0;
  auto alloc = [&](size_t bytes) -> void* {
    void* r = w + o;
    o = (o + bytes + 255) & ~(size_t)255;
    return r;
  };
  p.w0x = (u16*)alloc((size_t)2048 * JJ * 2);
  p.w0h = (u16*)alloc((size_t)2048 * JJ * 2);
  p.w1x = (u16*)alloc((size_t)2048 * JJ * 2);
  p.w1h = (u16*)alloc((size_t)2048 * JJ * 2);
  p.wv  = (u16*)alloc((size_t)2048 * VV * 2);
  p.rs0 = (float*)alloc(JJ * 4);
  p.adj_cnt  = (int*)alloc((size_t)BB * VV * 4);
  p.adj_cols = (int*)alloc((size_t)BB * VV * 64 * 4);
  p.h0 = (float*)alloc((size_t)BB * VV * 4);
  p.m0 = (float*)alloc((size_t)BB * VV * 4);
  p.h1 = (float*)alloc((size_t)BB * VV * 4);
  p.m1 = (float*)alloc((size_t)BB * VV * 4);
  p.chb = (float*)alloc(2 * BB * CC * 4);
  p.cm  = (float*)alloc(BB * CC * 4);
  p.g0p = (float*)alloc((size_t)32 * BB * JJ * 4);
  p.g1p = (float*)alloc((size_t)16 * BB * JJ * 4);
  p.p1p = (float*)alloc((size_t)16 * BB * JJ * 4);
  p.vmp = (float*)alloc((size_t)16 * BB * VV * 4);
  p.pacc = (float*)alloc(256);
  p.out = (float*)d_out;

  // setup: weight transpose+bf16, rowsum trick, adjacency list, state init
  kTrans<<<4096, 256, 0, stream>>>(p.v0_wih, 2 * VV, VV, 128, p.w0x, JJ);
  kTrans<<<4096, 256, 0, stream>>>(p.v0_whh, VV, 0, 128, p.w0h, JJ);
  kTrans<<<4096, 256, 0, stream>>>(p.v1_wih, VV, 0, 128, p.w1x, JJ);
  kTrans<<<4096, 256, 0, stream>>>(p.v1_whh, VV, 0, 128, p.w1h, JJ);
  kTrans<<<1024, 256, 0, stream>>>(p.vmsg_w, VV, 0, 32, p.wv, VV);
  kRs0<<<2048, 256, 0, stream>>>(p);
  kAdj<<<4096, 256, 0, stream>>>(p);
  kInit<<<64, 256, 0, stream>>>(p);

  for (int t = 0; t < TT; ++t) {
    kA<<<416, 256, 0, stream>>>(p);
    kB<<<65, 256, 0, stream>>>(p, t);
    kC<<<128, 256, 0, stream>>>(p);
    kD<<<64, 256, 0, stream>>>(p);
  }
  kV1<<<64, 256, 0, stream>>>(p);
  kV2<<<1, 64, 0, stream>>>(p);
}

// Round 2
// 3039.849 us; speedup vs baseline: 1.5777x; 1.5777x over previous
//
#include <hip/hip_runtime.h>
#include <math.h>

#define BB 8
#define VV 2048
#define CC 32
#define TT 32
#define JJ 8192   // 4*V

typedef unsigned short u16;
typedef unsigned int u32;
typedef short short8 __attribute__((ext_vector_type(8)));
typedef float f32x4 __attribute__((ext_vector_type(4)));

struct P {
  // inputs
  const float* Mvv; const int* ncol; const float* vh0; const float* ch0;
  const float* v0_wih; const float* v0_whh; const float* v0_bih; const float* v0_bhh;
  const float* v1_wih; const float* v1_whh; const float* v1_bih; const float* v1_bhh;
  const float* c_wih; const float* c_whh; const float* c_bih; const float* c_bhh;
  const float* cmsg_w; const float* cmsg_b; const float* vmsg_w; const float* vmsg_b;
  const float* vote_w; const float* vote_b;
  // workspace
  u16* w0xP; u16* w0hP; u16* w1xP; u16* w1hP; u16* wvP;   // packed B-frag weights
  u16* h0A; u16* h1A; u16* mvA;                            // packed A-frag activations (64KB each)
  float* rs0; int* adj_cnt; int* adj_cols;
  float* m0; float* h1; float* m1; float* chb; float* cm;
  float* g0p; float* g1p; float* p1p; float* vmp; float* pacc;
  float* out;
};

__device__ __forceinline__ u16 f2bf(float f) {
  u32 x = __float_as_uint(f);
  u32 r = (x + 0x7fffu + ((x >> 16) & 1u)) >> 16;
  return (u16)r;
}

__device__ __forceinline__ float sigm(float x) { return 1.f / (1.f + expf(-x)); }

// ============ setup kernels ============

// pack W[j][k] (row-major, stride `stride`, col offset colOff, K=2048 span) into
// MFMA-B tile order: tile (jt,kt) = 64 lanes x 8 bf16; lane holds
// B[k = kt*32 + (lane>>4)*8 + i][n = jt*16 + (lane&15)] = W[n][colOff + k]
__global__ __launch_bounds__(256) void kPack(const float* __restrict__ src, int stride, int colOff,
                                             u16* __restrict__ dst) {
  int tile = blockIdx.x * 4 + (threadIdx.x >> 6);
  int lane = threadIdx.x & 63;
  int jt = tile >> 6, kt = tile & 63;            // KT = 64 tiles along K for all mats
  int j = jt * 16 + (lane & 15);
  int k = colOff + kt * 32 + ((lane >> 4) << 3);
  const float* sp = src + (size_t)j * stride + k;
  float4 a = *(const float4*)sp;
  float4 b = *(const float4*)(sp + 4);
  uint4 pk;
  pk.x = (u32)f2bf(a.x) | ((u32)f2bf(a.y) << 16);
  pk.y = (u32)f2bf(a.z) | ((u32)f2bf(a.w) << 16);
  pk.z = (u32)f2bf(b.x) | ((u32)f2bf(b.y) << 16);
  pk.w = (u32)f2bf(b.z) | ((u32)f2bf(b.w) << 16);
  *(uint4*)(dst + (size_t)tile * 512 + lane * 8) = pk;
}

// rs0[j] = sum_{k<2048} v0_wih[j][k]  (muled_c broadcast-column trick)
__global__ __launch_bounds__(256) void kRs0(P p) {
  int wid = threadIdx.x >> 6, lane = threadIdx.x & 63;
  int row = blockIdx.x * 4 + wid;
  const float* sp = p.v0_wih + (size_t)row * (2 * VV);
  float s = 0.f;
  for (int i = lane; i < VV; i += 64) s += sp[i];
#pragma unroll
  for (int d = 32; d > 0; d >>= 1) s += __shfl_down(s, d, 64);
  if (lane == 0) p.rs0[row] = s;
}

// adjacency list: one wave per (b,u) row of Mvv
__global__ __launch_bounds__(256) void kAdj(P p) {
  int wid = threadIdx.x >> 6, lane = threadIdx.x & 63;
  int row = blockIdx.x * 4 + wid;   // b*2048+u
  const float* mp = p.Mvv + (size_t)row * VV;
  int* cols = p.adj_cols + (size_t)row * 64;
  int cnt = 0;
  for (int it = 0; it < 32; ++it) {
    float v = mp[it * 64 + lane];
    bool nz = v > 0.5f;
    unsigned long long mk = __ballot(nz);
    if (nz) {
      int pos = cnt + (int)__popcll(mk & ((1ull << lane) - 1ull));
      if (pos < 64) cols[pos] = it * 64 + lane;
    }
    cnt += (int)__popcll(mk);
  }
  if (lane == 0) p.adj_cnt[row] = cnt > 64 ? 64 : cnt;
}

// one u32 slot of a packed-A buffer from fp32 source X[8][2048] (rows 8..15 -> 0)
__device__ __forceinline__ u32 apack_slot(const float* __restrict__ X, int slot) {
  int kt = slot >> 8;                 // 256 u32 per 1KB tile
  int r = slot & 255;
  int lane = r >> 2, w = r & 3;
  int b = lane & 15;
  if (b >= 8) return 0u;
  int k = kt * 32 + ((lane >> 4) << 3) + w * 2;
  return (u32)f2bf(X[b * VV + k]) | ((u32)f2bf(X[b * VV + k + 1]) << 16);
}

__global__ __launch_bounds__(256) void kInit(P p) {
  int i = blockIdx.x * 256 + threadIdx.x;  // 16384
  p.m0[i] = 0.f; p.m1[i] = 0.f;
  p.h1[i] = p.vh0[BB * VV + i];
  ((u32*)p.h0A)[i] = apack_slot(p.vh0, i);
  ((u32*)p.h1A)[i] = apack_slot(p.vh0 + BB * VV, i);
  ((u32*)p.mvA)[i] = 0u;
  if (i < BB * CC) { p.chb[i] = p.ch0[i]; p.cm[i] = 0.f; }
  if (i < 8) p.pacc[i] = 0.f;
}

// write one value into packed-A layout
__device__ __forceinline__ void apack_write(u16* __restrict__ A, int b, int u, float v) {
  int kt = u >> 5, sub = (u >> 3) & 3, i = u & 7;
  A[((size_t)(kt * 64 + sub * 16 + b)) * 8 + i] = f2bf(v);
}

// ============ per-step kernels ============

// gather muled_v[b][u] = sum_{v in adj} h1[b][v] -> packed-A bf16
__global__ __launch_bounds__(256) void kG(P p) {
  int flat = blockIdx.x * 256 + threadIdx.x;   // b*2048+u
  int b = flat >> 11, u = flat & 2047;
  int cnt = p.adj_cnt[flat];
  const int* cp = p.adj_cols + (size_t)flat * 64;
  const float* hb = p.h1 + b * VV;
  float s = 0.f;
  for (int q = 0; q < cnt; ++q) s += hb[cp[q]];
  apack_write(p.mvA, b, u, s);
}

__device__ __forceinline__ void mma_chunk(const short8* __restrict__ ap,
                                          const short8* __restrict__ bp,
                                          f32x4& acc) {
#pragma unroll 4
  for (int kt = 0; kt < 16; ++kt) {
    short8 a = ap[(size_t)kt * 64];
    short8 b = bp[(size_t)kt * 64];
    acc = __builtin_amdgcn_mfma_f32_16x16x32_bf16(a, b, acc, 0, 0, 0);
  }
}

__device__ __forceinline__ void store_part(float* __restrict__ out, int OJ,
                                           int jt, int lane, f32x4 acc) {
  int n = lane & 15, rq = lane >> 4;
  if (rq < 2) {
    float* op = out + (size_t)(rq * 4) * OJ + jt * 16 + n;
#pragma unroll
    for (int r = 0; r < 4; ++r) op[(size_t)r * OJ] = acc[r];
  }
}

// kA: gates0 partials (w0x@mvA + w0h@h0A), part1 (w1h@h1A), vmsg (wv@h1A)
__global__ __launch_bounds__(256) void kA(P p) {
  int bx = blockIdx.x, tid = threadIdx.x;
  int wv_ = tid >> 6, lane = tid & 63;
  f32x4 acc = {0.f, 0.f, 0.f, 0.f};
  if (bx < 512) {
    int s = bx & 3, jb = bx >> 2;
    int jt = jb * 4 + wv_;                 // 0..511
    int ktb = s * 16;
    mma_chunk((const short8*)p.mvA + (size_t)ktb * 64 + lane,
              (const short8*)p.w0xP + ((size_t)jt * 64 + ktb) * 64 + lane, acc);
    mma_chunk((const short8*)p.h0A + (size_t)ktb * 64 + lane,
              (const short8*)p.w0hP + ((size_t)jt * 64 + ktb) * 64 + lane, acc);
    store_part(p.g0p + (size_t)s * BB * JJ, JJ, jt, lane, acc);
  } else if (bx < 1024) {
    int i = bx - 512; int s = i & 3, jb = i >> 2;
    int jt = jb * 4 + wv_;
    int ktb = s * 16;
    mma_chunk((const short8*)p.h1A + (size_t)ktb * 64 + lane,
              (const short8*)p.w1hP + ((size_t)jt * 64 + ktb) * 64 + lane, acc);
    store_part(p.p1p + (size_t)s * BB * JJ, JJ, jt, lane, acc);
  } else {
    int i = bx - 1024; int s = i & 3, jb = i >> 2;   // jb 0..31
    int jt = jb * 4 + wv_;                            // 0..127
    int ktb = s * 16;
    mma_chunk((const short8*)p.h1A + (size_t)ktb * 64 + lane,
              (const short8*)p.wvP + ((size_t)jt * 64 + ktb) * 64 + lane, acc);
    store_part(p.vmp + (size_t)s * BB * VV, VV, jt, lane, acc);
  }
}

// kB: blocks 0-63 reduce gates0 -> h0'; block 64: color LSTM (vmsg reduce + cell)
__global__ __launch_bounds__(256) void kB(P p, int t) {
  int bx = blockIdx.x, tid = threadIdx.x;
  const float* chp = p.chb + (t & 1) * BB * CC;
  float* chq = p.chb + ((t + 1) & 1) * BB * CC;
  if (bx < 64) {
    __shared__ float scv[BB];
    __shared__ float scs[BB * CC];
    {
      int b = tid >> 5, jc = tid & 31;
      float a = p.cmsg_b[jc];
#pragma unroll
      for (int k = 0; k < 32; ++k) a += chp[b * CC + k] * p.cmsg_w[jc * CC + k];
      a = fmaxf(a, 0.f);
      scs[tid] = (jc < p.ncol[b]) ? a : 0.f;
    }
    __syncthreads();
    if (tid < 8) {
      float s = 0.f;
      for (int jc = 0; jc < 32; ++jc) s += scs[tid * 32 + jc];
      scv[tid] = s;
    }
    __syncthreads();
    int flat = bx * 256 + tid;            // b*2048 + u
    int b = flat >> 11, u = flat & 2047;
    float g4[4];
#pragma unroll
    for (int g = 0; g < 4; ++g) {
      int jj = g * 2048 + u;
      float s = p.v0_bih[jj] + p.v0_bhh[jj] + scv[b] * p.rs0[jj];
      const float* gp = p.g0p + (size_t)b * JJ + jj;
#pragma unroll
      for (int sl = 0; sl < 4; ++sl) s += gp[(size_t)sl * BB * JJ];
      g4[g] = s;
    }
    float ig = sigm(g4[0]), fg = sigm(g4[1]), gg = tanhf(g4[2]), og = sigm(g4[3]);
    float mn = fg * p.m0[flat] + ig * gg;
    float hn = og * tanhf(mn);
    p.m0[flat] = mn;
    apack_write(p.h0A, b, u, hn);
  } else {
    __shared__ float red[256];
    __shared__ float vs[BB];
    for (int b = 0; b < 8; ++b) {
      float ps = 0.f;
      for (int uu = tid; uu < VV; uu += 256) {
        float s = p.vmsg_b[uu];
        const float* vp = p.vmp + (size_t)b * VV + uu;
#pragma unroll
        for (int sl = 0; sl < 4; ++sl) s += vp[(size_t)sl * BB * VV];
        ps += fmaxf(s, 0.f);
      }
      red[tid] = ps;
      __syncthreads();
      for (int d = 128; d > 0; d >>= 1) {
        if (tid < d) red[tid] += red[tid + d];
        __syncthreads();
      }
      if (tid == 0) vs[b] = red[0];
      __syncthreads();
    }
    int b = tid >> 5, tc = tid & 31;
    int nc = p.ncol[b];
    float g4[4];
#pragma unroll
    for (int g = 0; g < 4; ++g) {
      int jc = g * 32 + tc;
      float s = p.c_bih[jc] + p.c_bhh[jc];
      float wsum = 0.f;
      for (int k = 0; k < nc; ++k) wsum += p.c_wih[jc * CC + k];
      s += vs[b] * wsum;
#pragma unroll
      for (int k = 0; k < 32; ++k) s += chp[b * CC + k] * p.c_whh[jc * CC + k];
      g4[g] = s;
    }
    float ig = sigm(g4[0]), fg = sigm(g4[1]), gg = tanhf(g4[2]), og = sigm(g4[3]);
    float mn = fg * p.cm[tid] + ig * gg;
    float hn = og * tanhf(mn);
    p.cm[tid] = mn; chq[tid] = hn;
  }
}

// kC: gates1 partials = w1x @ h0A(new)
__global__ __launch_bounds__(256) void kC(P p) {
  int bx = blockIdx.x, tid = threadIdx.x;
  int wv_ = tid >> 6, lane = tid & 63;
  int s = bx & 3, jb = bx >> 2;
  int jt = jb * 4 + wv_;
  int ktb = s * 16;
  f32x4 acc = {0.f, 0.f, 0.f, 0.f};
  mma_chunk((const short8*)p.h0A + (size_t)ktb * 64 + lane,
            (const short8*)p.w1xP + ((size_t)jt * 64 + ktb) * 64 + lane, acc);
  store_part(p.g1p + (size_t)s * BB * JJ, JJ, jt, lane, acc);
}

// kD: reduce gates1 + part1 -> h1'
__global__ __launch_bounds__(256) void kD(P p) {
  int bx = blockIdx.x, tid = threadIdx.x;
  int flat = bx * 256 + tid;
  int b = flat >> 11, u = flat & 2047;
  float g4[4];
#pragma unroll
  for (int g = 0; g < 4; ++g) {
    int jj = g * 2048 + u;
    float s = p.v1_bih[jj] + p.v1_bhh[jj];
    const float* gp = p.g1p + (size_t)b * JJ + jj;
    const float* pp = p.p1p + (size_t)b * JJ + jj;
#pragma unroll
    for (int sl = 0; sl < 4; ++sl) s += gp[(size_t)sl * BB * JJ] + pp[(size_t)sl * BB * JJ];
    g4[g] = s;
  }
  float ig = sigm(g4[0]), fg = sigm(g4[1]), gg = tanhf(g4[2]), og = sigm(g4[3]);
  float mn = fg * p.m1[flat] + ig * gg;
  float hn = og * tanhf(mn);
  p.m1[flat] = mn; p.h1[flat] = hn;
  apack_write(p.h1A, b, u, hn);
}

// vote
__global__ __launch_bounds__(256) void kV1(P p) {
  int bx = blockIdx.x, tid = threadIdx.x;
  int b = bx >> 3, ut = bx & 7;
  int u = ut * 256 + tid;
  __shared__ float hs[VV];
  for (int i = tid; i < VV; i += 256) hs[i] = p.h1[b * VV + i];
  __syncthreads();
  const float* wr = p.vote_w + (size_t)u * VV;
  float s = p.vote_b[u];
  for (int k = 0; k < VV; k += 4) {
    float4 w = *(const float4*)(wr + k);
    s += w.x * hs[k] + w.y * hs[k + 1] + w.z * hs[k + 2] + w.w * hs[k + 3];
  }
  atomicAdd(&p.pacc[b], sigm(s));
}

__global__ __launch_bounds__(64) void kV2(P p) {
  int tid = threadIdx.x;
  if (tid < 8) p.out[tid] = sigm(p.pacc[tid] * (1.f / (float)VV));
}

extern "C" void kernel_launch(void* const* d_in, const int* in_sizes, int n_in,
                              void* d_out, int out_size, void* d_ws, size_t ws_size,
                              hipStream_t stream) {
  P p;
  p.Mvv    = (const float*)d_in[0];
  p.ncol   = (const int*)d_in[1];
  p.vh0    = (const float*)d_in[2];
  p.ch0    = (const float*)d_in[3];
  p.v0_wih = (const float*)d_in[4];
  p.v0_whh = (const float*)d_in[5];
  p.v0_bih = (const float*)d_in[6];
  p.v0_bhh = (const float*)d_in[7];
  p.v1_wih = (const float*)d_in[8];
  p.v1_whh = (const float*)d_in[9];
  p.v1_bih = (const float*)d_in[10];
  p.v1_bhh = (const float*)d_in[11];
  p.c_wih  = (const float*)d_in[12];
  p.c_whh  = (const float*)d_in[13];
  p.c_bih  = (const float*)d_in[14];
  p.c_bhh  = (const float*)d_in[15];
  p.cmsg_w = (const float*)d_in[16];
  p.cmsg_b = (const float*)d_in[17];
  p.vmsg_w = (const float*)d_in[18];
  p.vmsg_b = (const float*)d_in[19];
  p.vote_w = (const float*)d_in[20];
  p.vote_b = (const float*)d_in[21];

  char* w = (char*)d_ws;
  size_t o = 0;
  auto alloc = [&](size_t bytes) -> void* {
    void* r = w + o;
    o = (o + bytes + 255) & ~(size_t)255;
    return r;
  };
  p.w0xP = (u16*)alloc((size_t)512 * 64 * 1024);   // 32MB
  p.w0hP = (u16*)alloc((size_t)512 * 64 * 1024);
  p.w1xP = (u16*)alloc((size_t)512 * 64 * 1024);
  p.w1hP = (u16*)alloc((size_t)512 * 64 * 1024);
  p.wvP  = (u16*)alloc((size_t)128 * 64 * 1024);   // 8MB
  p.h0A  = (u16*)alloc(64 * 1024);
  p.h1A  = (u16*)alloc(64 * 1024);
  p.mvA  = (u16*)alloc(64 * 1024);
  p.rs0 = (float*)alloc(JJ * 4);
  p.adj_cnt  = (int*)alloc((size_t)BB * VV * 4);
  p.adj_cols = (int*)alloc((size_t)BB * VV * 64 * 4);
  p.m0 = (float*)alloc((size_t)BB * VV * 4);
  p.h1 = (float*)alloc((size_t)BB * VV * 4);
  p.m1 = (float*)alloc((size_t)BB * VV * 4);
  p.chb = (float*)alloc(2 * BB * CC * 4);
  p.cm  = (float*)alloc(BB * CC * 4);
  p.g0p = (float*)alloc((size_t)4 * BB * JJ * 4);
  p.g1p = (float*)alloc((size_t)4 * BB * JJ * 4);
  p.p1p = (float*)alloc((size_t)4 * BB * JJ * 4);
  p.vmp = (float*)alloc((size_t)4 * BB * VV * 4);
  p.pacc = (float*)alloc(256);
  p.out = (float*)d_out;

  // setup: pack weights to MFMA-B tiles, rowsum trick, adjacency, state init
  kPack<<<8192, 256, 0, stream>>>(p.v0_wih, 2 * VV, VV, p.w0xP);
  kPack<<<8192, 256, 0, stream>>>(p.v0_whh, VV, 0, p.w0hP);
  kPack<<<8192, 256, 0, stream>>>(p.v1_wih, VV, 0, p.w1xP);
  kPack<<<8192, 256, 0, stream>>>(p.v1_whh, VV, 0, p.w1hP);
  kPack<<<2048, 256, 0, stream>>>(p.vmsg_w, VV, 0, p.wvP);
  kRs0<<<2048, 256, 0, stream>>>(p);
  kAdj<<<4096, 256, 0, stream>>>(p);
  kInit<<<64, 256, 0, stream>>>(p);

  for (int t = 0; t < TT; ++t) {
    kG<<<64, 256, 0, stream>>>(p);
    kA<<<1152, 256, 0, stream>>>(p);
    kB<<<65, 256, 0, stream>>>(p, t);
    kC<<<512, 256, 0, stream>>>(p);
    kD<<<64, 256, 0, stream>>>(p);
  }
  kV1<<<64, 256, 0, stream>>>(p);
  kV2<<<1, 64, 0, stream>>>(p);
}